// Round 7
// baseline (126.362 us; speedup 1.0000x reference)
//
#include <hip/hip_runtime.h>

#define IN_NUM 1152
#define OUT_NUM 10
#define OUT_DIM 16
#define IN_DIM 8
#define NB 256
#define KTOT 9216

// workspace float offsets
#define OFF_SPART 0
#define SZ_SPART (96 * OUT_NUM * OUT_DIM * NB)        // 3,932,160
#define OFF_VT (OFF_SPART + SZ_SPART)
#define SZ_VT (NB * OUT_NUM * OUT_DIM)                // 40,960
#define OFF_BP (OFF_VT + SZ_VT)
#define SZ_BP (32 * IN_NUM * OUT_NUM)                 // 368,640 (4 b-quarters x 8 c)
#define OFF_WT (OFF_BP + SZ_BP)
#define SZ_WT (OUT_NUM * OUT_DIM * IN_DIM * IN_NUM)   // 1,474,560

#define SMEM_FLOATS 5792   // 23,168 B per block

// ---- phase 1: spart[isp][j][d][b] = sum_{k in chunk} c[i,j]W[i,j,d,c] * x[b][k] ----
// 128 threads: 64 bb (x4 b via float4) x 2 dg (x8 d). VALU:LDS = 64:36 cyc per kk.
// At it==0 additionally materializes Wt[j][d][c][i] (raw W transpose) for phase 3.
__device__ __forceinline__ void phase1(float* smem, int t, int w, int it,
                                       const float* __restrict__ x, const float* __restrict__ W,
                                       float* __restrict__ Wt,
                                       const float* __restrict__ bp, float* __restrict__ spart) {
    int g8 = w / 80, r = w - g8 * 80;
    int j = r >> 3, isp = g8 * 8 + (r & 7);   // same-isp blocks 8 apart -> same XCD
    int cch = isp / 12;
    int i0 = (isp - cch * 12) * 96;
    int k0 = isp * 96;
    float (*xt)[260] = (float (*)[260])smem;           // 16 x 260 = 4160
    float (*at)[16]  = (float (*)[16])(smem + 4160);   // 96 x 16 = 1536
    float* ldc = smem + 5696;                          // 96
    if (t < 96) {
        float cv;
        if (it == 0) {
            cv = 0.1f;
        } else {
            int i = i0 + t;
            float bt_[OUT_NUM];
#pragma unroll
            for (int jp = 0; jp < OUT_NUM; ++jp) bt_[jp] = 0.f;
#pragma unroll
            for (int row = 0; row < 32; ++row) {   // 4 quarters x 8 c partial rows
                const float* p = &bp[((size_t)row * IN_NUM + i) * OUT_NUM];
#pragma unroll
                for (int jp = 0; jp < OUT_NUM; ++jp) bt_[jp] += p[jp];
            }
            float m = -1e30f;
#pragma unroll
            for (int jp = 0; jp < OUT_NUM; ++jp) { bt_[jp] *= (1.f / NB); m = fmaxf(m, bt_[jp]); }
            float s = 0.f;
#pragma unroll
            for (int jp = 0; jp < OUT_NUM; ++jp) { bt_[jp] = __expf(bt_[jp] - m); s += bt_[jp]; }
            cv = bt_[j] / s;
        }
        ldc[t] = cv;
    }
    __syncthreads();
    if (it == 0) {
        // build at from raw W; also emit Wt slice (one-time transpose, coalesced over kk)
        for (int e = t; e < 1536; e += 128) {
            int d = e / 96, kk = e - d * 96;
            float raw = W[(size_t)(i0 + kk) * 1280 + j * 128 + d * 8 + cch];
            Wt[(size_t)(j * 16 + d) * KTOT + cch * IN_NUM + i0 + kk] = raw;
            at[kk][d] = 0.1f * raw;
        }
    } else {
        for (int e = t; e < 1536; e += 128) {
            int d = e / 96, kk = e - d * 96;
            at[kk][d] = ldc[kk] * Wt[(size_t)(j * 16 + d) * KTOT + cch * IN_NUM + i0 + kk];
        }
    }
    int bb = t & 63, dg = t >> 6;          // dg in {0,1}: 8 d's each
    int q4 = t & 3, row = t >> 2;          // staging map: 4 k-quads x 32 b-rows
    float acc[32];
#pragma unroll
    for (int q = 0; q < 32; ++q) acc[q] = 0.f;
    for (int ch = 0; ch < 6; ++ch) {
        __syncthreads();
#pragma unroll
        for (int rr = 0; rr < 8; ++rr) {
            int b = rr * 32 + row;
            float4 xv = *reinterpret_cast<const float4*>(
                &x[(size_t)b * KTOT + k0 + ch * 16 + q4 * 4]);
            xt[q4 * 4 + 0][b] = xv.x; xt[q4 * 4 + 1][b] = xv.y;
            xt[q4 * 4 + 2][b] = xv.z; xt[q4 * 4 + 3][b] = xv.w;
        }
        __syncthreads();
#pragma unroll
        for (int kk = 0; kk < 16; ++kk) {
            float4 xv = *reinterpret_cast<const float4*>(&xt[kk][bb * 4]);
            float4 a0 = *reinterpret_cast<const float4*>(&at[ch * 16 + kk][dg * 8]);      // uniform -> broadcast
            float4 a1 = *reinterpret_cast<const float4*>(&at[ch * 16 + kk][dg * 8 + 4]);  // uniform -> broadcast
            acc[0]  += a0.x * xv.x; acc[1]  += a0.x * xv.y; acc[2]  += a0.x * xv.z; acc[3]  += a0.x * xv.w;
            acc[4]  += a0.y * xv.x; acc[5]  += a0.y * xv.y; acc[6]  += a0.y * xv.z; acc[7]  += a0.y * xv.w;
            acc[8]  += a0.z * xv.x; acc[9]  += a0.z * xv.y; acc[10] += a0.z * xv.z; acc[11] += a0.z * xv.w;
            acc[12] += a0.w * xv.x; acc[13] += a0.w * xv.y; acc[14] += a0.w * xv.z; acc[15] += a0.w * xv.w;
            acc[16] += a1.x * xv.x; acc[17] += a1.x * xv.y; acc[18] += a1.x * xv.z; acc[19] += a1.x * xv.w;
            acc[20] += a1.y * xv.x; acc[21] += a1.y * xv.y; acc[22] += a1.y * xv.z; acc[23] += a1.y * xv.w;
            acc[24] += a1.z * xv.x; acc[25] += a1.z * xv.y; acc[26] += a1.z * xv.z; acc[27] += a1.z * xv.w;
            acc[28] += a1.w * xv.x; acc[29] += a1.w * xv.y; acc[30] += a1.w * xv.z; acc[31] += a1.w * xv.w;
        }
    }
    float* sp = spart + (size_t)(isp * OUT_NUM + j) * (OUT_DIM * NB);
#pragma unroll
    for (int dd = 0; dd < 8; ++dd) {
        float4 o;
        o.x = acc[dd * 4 + 0]; o.y = acc[dd * 4 + 1];
        o.z = acc[dd * 4 + 2]; o.w = acc[dd * 4 + 3];
        *reinterpret_cast<float4*>(&sp[(dg * 8 + dd) * NB + bb * 4]) = o;
    }
}

// ---- phase 2: reduce spart over isp, squash, write dst[b][j][d] ----
__device__ __forceinline__ void phase2(float* smem, int t, int w,
                                       const float* __restrict__ spart, float* __restrict__ dst) {
    float (*red)[32][17] = (float (*)[32][17])smem;    // 4352
    float (*nrm)[9] = (float (*)[9])(smem + 4352);     // 288
    float* cf = smem + 4640;                           // 32
    int j = w >> 3, bt2 = w & 7;
    int ie = t >> 5, bb = t & 31;
    int b = bt2 * 32 + bb;
    float acc[16];
#pragma unroll
    for (int d = 0; d < 16; ++d) acc[d] = 0.f;
    for (int q = 0; q < 12; ++q) {
        int isp = ie * 12 + q;
        const float* sp = spart + (size_t)(isp * OUT_NUM + j) * (OUT_DIM * NB) + b;
#pragma unroll
        for (int d = 0; d < 16; ++d) acc[d] += sp[d * NB];
    }
#pragma unroll
    for (int d = 0; d < 16; ++d) red[ie][bb][d] = acc[d];
    __syncthreads();
    int bb2 = t >> 3, dp = t & 7;
    float s0 = 0.f, s1 = 0.f;
#pragma unroll
    for (int e = 0; e < 8; ++e) { s0 += red[e][bb2][dp * 2]; s1 += red[e][bb2][dp * 2 + 1]; }
    nrm[bb2][dp] = s0 * s0 + s1 * s1;
    __syncthreads();
    if (t < 32) {
        float qn = 0.f;
#pragma unroll
        for (int d = 0; d < 8; ++d) qn += nrm[t][d];
        cf[t] = qn / ((1.f + qn) * sqrtf(qn));
    }
    __syncthreads();
    float cs = cf[bb2];
    float* o = dst + (size_t)(bt2 * 32 + bb2) * (OUT_NUM * OUT_DIM) + j * OUT_DIM + dp * 2;
    o[0] = s0 * cs;
    o[1] = s1 * cs;
}

// ---- phase 3: bp[bq*8+c][i][j] = prev + sum_d Wt[j][d][k] * sum_{b in quarter} vt[b][j][d]*x[b][k] ----
// (j, bq) block-uniform -> vt loads scalarize (s_load); x loads coalesced; no LDS.
__device__ __forceinline__ void phase3(int u, int t, int it,
                                       const float* __restrict__ x, const float* __restrict__ vt,
                                       const float* __restrict__ Wt, float* __restrict__ bp) {
    int kt = u % 36;            // k-tile of 256
    int jq = u / 36;            // 0..39
    int j = jq >> 2, bq = jq & 3;
    int k = kt * 256 + t;
    int c = k / IN_NUM, i = k - c * IN_NUM;
    const float* xk = x + k + (size_t)(bq * 64) * KTOT;
    const float* vjb = vt + (size_t)(bq * 64) * (OUT_NUM * OUT_DIM) + j * OUT_DIM;
    float macc[16];
#pragma unroll
    for (int d = 0; d < 16; ++d) macc[d] = 0.f;
#pragma unroll 8
    for (int b = 0; b < 64; ++b) {
        float xv = xk[(size_t)b * KTOT];
        const float* vb = vjb + (size_t)b * (OUT_NUM * OUT_DIM);   // block-uniform -> s_load
#pragma unroll
        for (int d = 0; d < 16; ++d) macc[d] += vb[d] * xv;
    }
    float bs = 0.f;
#pragma unroll
    for (int d = 0; d < 16; ++d)
        bs += macc[d] * Wt[(size_t)(j * OUT_DIM + d) * KTOT + k];
    size_t idx = (size_t)(bq * 8 + c) * (IN_NUM * OUT_NUM) + (size_t)i * OUT_NUM + j;
    float prev = (it == 0) ? 0.f : bp[idx];
    bp[idx] = prev + bs;
}

// ================= kernels =================
__global__ __launch_bounds__(128, 4) void k_p1(const float* __restrict__ x, const float* __restrict__ W,
                                               float* __restrict__ ws, int it) {
    __shared__ float smem[SMEM_FLOATS];
    phase1(smem, threadIdx.x, blockIdx.x, it, x, W, ws + OFF_WT, ws + OFF_BP, ws + OFF_SPART);
}
__global__ __launch_bounds__(256, 4) void k_p2(const float* __restrict__ ws, float* __restrict__ dst) {
    __shared__ float smem[SMEM_FLOATS];
    phase2(smem, threadIdx.x, blockIdx.x, ws + OFF_SPART, dst);
}
__global__ __launch_bounds__(256) void k_p3(const float* __restrict__ x, float* __restrict__ ws, int it) {
    phase3(blockIdx.x, threadIdx.x, it, x, ws + OFF_VT, ws + OFF_WT, ws + OFF_BP);
}

extern "C" void kernel_launch(void* const* d_in, const int* in_sizes, int n_in,
                              void* d_out, int out_size, void* d_ws, size_t ws_size,
                              hipStream_t stream) {
    const float* x = (const float*)d_in[0];   // [256][8][1152]
    const float* W = (const float*)d_in[1];   // [1152][10][16][8]
    float* out = (float*)d_out;               // [256][10][16][1]
    float* ws = (float*)d_ws;

    for (int it = 0; it < 3; ++it) {
        k_p1<<<dim3(960), dim3(128), 0, stream>>>(x, W, ws, it);
        k_p2<<<dim3(80), dim3(256), 0, stream>>>(ws, it == 2 ? out : (ws + OFF_VT));
        if (it < 2) k_p3<<<dim3(1440), dim3(256), 0, stream>>>(x, ws, it);
    }
}